// Round 1
// baseline (38.767 us; speedup 1.0000x reference)
//
#include <hip/hip_runtime.h>
#include <math.h>

// Problem constants (reference shapes are fixed)
#define S_LEN 2048
#define NB 4
#define NH 4
#define BHN 16                      // NB*NH
#define E_DIM 12
#define NKB 8                       // key-split factor
#define KEYS_PER_KB (S_LEN / NKB)   // 256
#define NQT 8                       // query tiles per (b,h)
#define QT_SIZE (S_LEN / NQT)       // 256 queries per block
// log2(e)/sqrt(3): fold softmax 1/sqrt(d) scale + exp->exp2 conversion into Q
#define QSCALE 0.8329931278350429f

// ---------------- Kernel 0: QKV projection ----------------
// Q stored pre-scaled; V.w = 1.0 so the attention FMA accumulates the softmax
// denominator in acc.w for free.
__global__ __launch_bounds__(128) void qkv_kernel(
    const float* __restrict__ x, const float* __restrict__ wq,
    const float* __restrict__ wk, const float* __restrict__ wv,
    float4* __restrict__ Q, float4* __restrict__ K, float4* __restrict__ V)
{
    __shared__ float swq[144], swk[144], swv[144];
    int tid = threadIdx.x;
    for (int i = tid; i < 144; i += 128) { swq[i] = wq[i]; swk[i] = wk[i]; swv[i] = wv[i]; }
    __syncthreads();

    int t = blockIdx.x * 128 + tid;          // token 0..8191
    int b = t >> 11;
    int s = t & (S_LEN - 1);

    const float4* xp = (const float4*)(x + (size_t)t * E_DIM);
    float4 xa = xp[0], xb = xp[1], xc = xp[2];
    float xr[12] = {xa.x, xa.y, xa.z, xa.w, xb.x, xb.y, xb.z, xb.w, xc.x, xc.y, xc.z, xc.w};

#pragma unroll
    for (int h = 0; h < NH; ++h) {
        float q0 = 0, q1 = 0, q2 = 0, k0 = 0, k1 = 0, k2 = 0, v0 = 0, v1 = 0, v2 = 0;
#pragma unroll
        for (int e = 0; e < 12; ++e) {
            float xe = xr[e];
            int c = e * 12 + h * 3;
            q0 = fmaf(xe, swq[c + 0], q0);
            q1 = fmaf(xe, swq[c + 1], q1);
            q2 = fmaf(xe, swq[c + 2], q2);
            k0 = fmaf(xe, swk[c + 0], k0);
            k1 = fmaf(xe, swk[c + 1], k1);
            k2 = fmaf(xe, swk[c + 2], k2);
            v0 = fmaf(xe, swv[c + 0], v0);
            v1 = fmaf(xe, swv[c + 1], v1);
            v2 = fmaf(xe, swv[c + 2], v2);
        }
        size_t idx = (size_t)(b * NH + h) * S_LEN + s;
        Q[idx] = make_float4(q0 * QSCALE, q1 * QSCALE, q2 * QSCALE, 0.0f);
        K[idx] = make_float4(k0, k1, k2, 0.0f);
        V[idx] = make_float4(v0, v1, v2, 1.0f);
    }
}

// ---------------- Kernel 1: attention partials ----------------
// grid = BHN * NQT * NKB blocks of 256 threads.
// Block handles (bh, 256-query tile, 256-key slice). Each of 4 waves takes a
// 64-key subrange; each lane register-tiles 4 queries. No max-subtraction:
// scores ~ N(0,1), exp2 in f32 is safe, and partials merge by plain adds.
__global__ __launch_bounds__(256) void attn_kernel(
    const float4* __restrict__ Q, const float4* __restrict__ K,
    const float4* __restrict__ V, float4* __restrict__ part)
{
    __shared__ float4 sK[KEYS_PER_KB];
    __shared__ float4 sV[KEYS_PER_KB];
    __shared__ float4 sAcc[4 * QT_SIZE];     // 16 KB wave-partial buffer

    int tid = threadIdx.x;
    int kb = blockIdx.x & (NKB - 1);
    int qt = (blockIdx.x / NKB) & (NQT - 1);
    int bh = blockIdx.x / (NKB * NQT);

    size_t kvbase = (size_t)bh * S_LEN + kb * KEYS_PER_KB;
    sK[tid] = K[kvbase + tid];
    sV[tid] = V[kvbase + tid];
    __syncthreads();

    int w = tid >> 6;
    int lane = tid & 63;

    float4 q[4];
    size_t qbase = (size_t)bh * S_LEN + qt * QT_SIZE;
#pragma unroll
    for (int r = 0; r < 4; ++r) q[r] = Q[qbase + r * 64 + lane];

    float4 acc[4];
#pragma unroll
    for (int r = 0; r < 4; ++r) acc[r] = make_float4(0.f, 0.f, 0.f, 0.f);

    int kbeg = w * 64;
#pragma unroll 4
    for (int j = 0; j < 64; ++j) {
        float4 kk = sK[kbeg + j];   // broadcast read (conflict-free)
        float4 vv = sV[kbeg + j];
#pragma unroll
        for (int r = 0; r < 4; ++r) {
            float sc = fmaf(q[r].x, kk.x, fmaf(q[r].y, kk.y, q[r].z * kk.z));
            float p = exp2f(sc);
            acc[r].x = fmaf(p, vv.x, acc[r].x);
            acc[r].y = fmaf(p, vv.y, acc[r].y);
            acc[r].z = fmaf(p, vv.z, acc[r].z);
            acc[r].w = fmaf(p, vv.w, acc[r].w);   // vv.w==1 -> denominator
        }
    }

    // block reduction across the 4 waves (each wave had a disjoint key range)
#pragma unroll
    for (int r = 0; r < 4; ++r) sAcc[w * QT_SIZE + r * 64 + lane] = acc[r];
    __syncthreads();

    float4 sum = sAcc[tid];
    float4 p1 = sAcc[QT_SIZE + tid];
    float4 p2 = sAcc[2 * QT_SIZE + tid];
    float4 p3 = sAcc[3 * QT_SIZE + tid];
    sum.x += p1.x + p2.x + p3.x;
    sum.y += p1.y + p2.y + p3.y;
    sum.z += p1.z + p2.z + p3.z;
    sum.w += p1.w + p2.w + p3.w;

    part[((size_t)kb * BHN + bh) * S_LEN + qt * QT_SIZE + tid] = sum;
}

// ---------------- Kernel 2: fused tail ----------------
// partial merge -> o -> theta -> closed-form ring_z -> @wo -> +x -> LN1 ->
// FFN (relu, cos^2) -> +res -> LN2 -> out.
// ring_z closed form: CNOT ring is GF(2)-linear; <Z_0> = prod_{j=1..11} cos(th_j),
// <Z_k> = prod_{j=0..k} cos(th_j) for k>=1.
__global__ __launch_bounds__(128) void tail_kernel(
    const float4* __restrict__ part, const float* __restrict__ x,
    const float* __restrict__ wo, const float* __restrict__ w1, const float* __restrict__ b1,
    const float* __restrict__ w2, const float* __restrict__ b2,
    const float* __restrict__ g1, const float* __restrict__ be1,
    const float* __restrict__ g2, const float* __restrict__ be2,
    float* __restrict__ out)
{
    __shared__ float swo[144], sw1[144], sw2[144];
    __shared__ float sb1[12], sb2[12], sg1[12], sbe1[12], sg2[12], sbe2[12];
    int tid = threadIdx.x;
    for (int i = tid; i < 144; i += 128) { swo[i] = wo[i]; sw1[i] = w1[i]; sw2[i] = w2[i]; }
    if (tid < 12) {
        sb1[tid] = b1[tid]; sb2[tid] = b2[tid];
        sg1[tid] = g1[tid]; sbe1[tid] = be1[tid];
        sg2[tid] = g2[tid]; sbe2[tid] = be2[tid];
    }
    __syncthreads();

    int t = blockIdx.x * 128 + tid;          // token
    int b = t >> 11;
    int s = t & (S_LEN - 1);

    // merge key-split partials, finish softmax division
    float o[12];
#pragma unroll
    for (int h = 0; h < NH; ++h) {
        int bh = b * NH + h;
        float ax = 0, ay = 0, az = 0, aw = 0;
#pragma unroll
        for (int kb = 0; kb < NKB; ++kb) {
            float4 p = part[((size_t)kb * BHN + bh) * S_LEN + s];
            ax += p.x; ay += p.y; az += p.z; aw += p.w;
        }
        float inv = 1.0f / aw;
        o[h * 3 + 0] = ax * inv;
        o[h * 3 + 1] = ay * inv;
        o[h * 3 + 2] = az * inv;
    }

    // theta_k = o_k + o_{k%3}; c_k = cos(theta_k)
    float c[12];
#pragma unroll
    for (int k = 0; k < 12; ++k) c[k] = __cosf(o[k] + o[k % 3]);

    // ring_z closed form
    float z[12];
    {
        float p = c[0];
#pragma unroll
        for (int k = 1; k < 12; ++k) { p *= c[k]; z[k] = p; }
        p = c[1];
#pragma unroll
        for (int k = 2; k < 12; ++k) p *= c[k];
        z[0] = p;
    }

    // attn_out = z @ wo ; residual with x
    const float4* xp = (const float4*)(x + (size_t)t * E_DIM);
    float4 xa = xp[0], xb = xp[1], xc = xp[2];
    float xr[12] = {xa.x, xa.y, xa.z, xa.w, xb.x, xb.y, xb.z, xb.w, xc.x, xc.y, xc.z, xc.w};

    float y[12];
#pragma unroll
    for (int e = 0; e < 12; ++e) {
        float ao = 0;
#pragma unroll
        for (int k = 0; k < 12; ++k) ao = fmaf(z[k], swo[k * 12 + e], ao);
        y[e] = xr[e] + ao;
    }

    // LN1
    float mu = 0;
#pragma unroll
    for (int e = 0; e < 12; ++e) mu += y[e];
    mu *= (1.0f / 12.0f);
    float var = 0;
#pragma unroll
    for (int e = 0; e < 12; ++e) { float d = y[e] - mu; var = fmaf(d, d, var); }
    var *= (1.0f / 12.0f);
    float rs = rsqrtf(var + 1e-5f);
    float x1v[12];
#pragma unroll
    for (int e = 0; e < 12; ++e) x1v[e] = (y[e] - mu) * rs * sg1[e] + sbe1[e];

    // FFN: relu -> cos^2 -> w2
    float zq[12];
#pragma unroll
    for (int f = 0; f < 12; ++f) {
        float hd = sb1[f];
#pragma unroll
        for (int e = 0; e < 12; ++e) hd = fmaf(x1v[e], sw1[e * 12 + f], hd);
        hd = fmaxf(hd, 0.0f);
        float cc = __cosf(hd);
        zq[f] = cc * cc;
    }
    float y2[12];
#pragma unroll
    for (int e = 0; e < 12; ++e) {
        float fo = sb2[e];
#pragma unroll
        for (int f = 0; f < 12; ++f) fo = fmaf(zq[f], sw2[f * 12 + e], fo);
        y2[e] = x1v[e] + fo;
    }

    // LN2 -> out
    float mu2 = 0;
#pragma unroll
    for (int e = 0; e < 12; ++e) mu2 += y2[e];
    mu2 *= (1.0f / 12.0f);
    float var2 = 0;
#pragma unroll
    for (int e = 0; e < 12; ++e) { float d = y2[e] - mu2; var2 = fmaf(d, d, var2); }
    var2 *= (1.0f / 12.0f);
    float rs2 = rsqrtf(var2 + 1e-5f);

    float res[12];
#pragma unroll
    for (int e = 0; e < 12; ++e) res[e] = (y2[e] - mu2) * rs2 * sg2[e] + sbe2[e];

    float4* op = (float4*)(out + (size_t)t * E_DIM);
    op[0] = make_float4(res[0], res[1], res[2], res[3]);
    op[1] = make_float4(res[4], res[5], res[6], res[7]);
    op[2] = make_float4(res[8], res[9], res[10], res[11]);
}

extern "C" void kernel_launch(void* const* d_in, const int* in_sizes, int n_in,
                              void* d_out, int out_size, void* d_ws, size_t ws_size,
                              hipStream_t stream)
{
    const float* x   = (const float*)d_in[0];
    const float* wq  = (const float*)d_in[1];
    const float* wk  = (const float*)d_in[2];
    const float* wv  = (const float*)d_in[3];
    const float* wo  = (const float*)d_in[4];
    const float* w1  = (const float*)d_in[5];
    const float* b1  = (const float*)d_in[6];
    const float* w2  = (const float*)d_in[7];
    const float* b2  = (const float*)d_in[8];
    const float* g1  = (const float*)d_in[9];
    const float* be1 = (const float*)d_in[10];
    const float* g2  = (const float*)d_in[11];
    const float* be2 = (const float*)d_in[12];

    float4* Q    = (float4*)d_ws;
    float4* K    = Q + (size_t)BHN * S_LEN;
    float4* V    = K + (size_t)BHN * S_LEN;
    float4* part = V + (size_t)BHN * S_LEN;   // NKB*BHN*S_LEN float4

    qkv_kernel<<<64, 128, 0, stream>>>(x, wq, wk, wv, Q, K, V);
    attn_kernel<<<BHN * NQT * NKB, 256, 0, stream>>>(Q, K, V, part);
    tail_kernel<<<64, 128, 0, stream>>>(part, x, wo, w1, b1, w2, b2,
                                        g1, be1, g2, be2, (float*)d_out);
}

// Round 2
// 27.887 us; speedup vs baseline: 1.3901x; 1.3901x over previous
//
#include <hip/hip_runtime.h>
#include <math.h>

// Problem constants (reference shapes are fixed)
#define S_LEN 2048
#define NB 4
#define NH 4
#define BHN 16                      // NB*NH
#define E_DIM 12
#define NKB 8                       // key-split factor
#define KEYS_PER_KB (S_LEN / NKB)   // 256
#define NQT 8                       // query tiles per (b,h)
#define QT_SIZE (S_LEN / NQT)       // 256 queries per block
// log2(e)/sqrt(3): fold softmax 1/sqrt(d) scale + exp->exp2 conversion into Q
#define QSCALE 0.8329931278350429f

// ---------------- Kernel 1: fused QKV-projection + attention partials ----------------
// grid = BHN * NQT * NKB blocks of 256 threads.
// Block handles (bh, 256-query tile, 256-key slice). It projects its own Q tile
// and K/V slice from x (27K FMAs, trivial vs the 524K-op inner loop), then each
// of 4 waves takes a 64-key subrange; each lane register-tiles 4 queries.
// No max-subtraction: scores ~ N(0,1), exp2 in f32 is safe, partials merge by adds.
__global__ __launch_bounds__(256) void attn_kernel(
    const float* __restrict__ x,
    const float* __restrict__ wq, const float* __restrict__ wk,
    const float* __restrict__ wv, float4* __restrict__ part)
{
    __shared__ float4 sK[KEYS_PER_KB];
    __shared__ float4 sV[KEYS_PER_KB];
    __shared__ float4 sQ[QT_SIZE];
    __shared__ float  sw[108];               // per-head weight cols: [q|k|v][e][d]
    __shared__ float4 sAcc[4 * QT_SIZE];     // 16 KB wave-partial buffer

    int tid = threadIdx.x;
    int kb = blockIdx.x & (NKB - 1);
    int qt = (blockIdx.x / NKB) & (NQT - 1);
    int bh = blockIdx.x / (NKB * NQT);
    int b  = bh >> 2;
    int h  = bh & 3;

    if (tid < 108) {
        int m = tid / 36;                    // 0=q, 1=k, 2=v
        int i = tid - m * 36;                // e*3 + d
        int e = i / 3, d = i - e * 3;
        const float* w = (m == 0) ? wq : (m == 1) ? wk : wv;
        sw[tid] = w[e * 12 + h * 3 + d];
    }
    __syncthreads();

    // ---- project this block's K/V slice and Q tile ----
    {
        size_t kt = (size_t)b * S_LEN + kb * KEYS_PER_KB + tid;
        const float4* xp = (const float4*)(x + kt * E_DIM);
        float4 xa = xp[0], xb = xp[1], xc = xp[2];
        float xr[12] = {xa.x, xa.y, xa.z, xa.w, xb.x, xb.y, xb.z, xb.w, xc.x, xc.y, xc.z, xc.w};
        float k0 = 0, k1 = 0, k2 = 0, v0 = 0, v1 = 0, v2 = 0;
#pragma unroll
        for (int e = 0; e < 12; ++e) {
            float xe = xr[e];
            k0 = fmaf(xe, sw[36 + e * 3 + 0], k0);
            k1 = fmaf(xe, sw[36 + e * 3 + 1], k1);
            k2 = fmaf(xe, sw[36 + e * 3 + 2], k2);
            v0 = fmaf(xe, sw[72 + e * 3 + 0], v0);
            v1 = fmaf(xe, sw[72 + e * 3 + 1], v1);
            v2 = fmaf(xe, sw[72 + e * 3 + 2], v2);
        }
        sK[tid] = make_float4(k0, k1, k2, 0.0f);
        sV[tid] = make_float4(v0, v1, v2, 1.0f);   // w==1 -> softmax denominator

        size_t qtk = (size_t)b * S_LEN + qt * QT_SIZE + tid;
        const float4* xq = (const float4*)(x + qtk * E_DIM);
        float4 qa = xq[0], qb = xq[1], qc = xq[2];
        float qr[12] = {qa.x, qa.y, qa.z, qa.w, qb.x, qb.y, qb.z, qb.w, qc.x, qc.y, qc.z, qc.w};
        float q0 = 0, q1 = 0, q2 = 0;
#pragma unroll
        for (int e = 0; e < 12; ++e) {
            float xe = qr[e];
            q0 = fmaf(xe, sw[e * 3 + 0], q0);
            q1 = fmaf(xe, sw[e * 3 + 1], q1);
            q2 = fmaf(xe, sw[e * 3 + 2], q2);
        }
        sQ[tid] = make_float4(q0 * QSCALE, q1 * QSCALE, q2 * QSCALE, 0.0f);
    }
    __syncthreads();

    int w = tid >> 6;
    int lane = tid & 63;

    float4 q[4];
#pragma unroll
    for (int r = 0; r < 4; ++r) q[r] = sQ[r * 64 + lane];

    float4 acc[4];
#pragma unroll
    for (int r = 0; r < 4; ++r) acc[r] = make_float4(0.f, 0.f, 0.f, 0.f);

    int kbeg = w * 64;
#pragma unroll 4
    for (int j = 0; j < 64; ++j) {
        float4 kk = sK[kbeg + j];   // broadcast read (conflict-free)
        float4 vv = sV[kbeg + j];
#pragma unroll
        for (int r = 0; r < 4; ++r) {
            float sc = fmaf(q[r].x, kk.x, fmaf(q[r].y, kk.y, q[r].z * kk.z));
            float p = __builtin_amdgcn_exp2f(sc);   // single v_exp_f32
            acc[r].x = fmaf(p, vv.x, acc[r].x);
            acc[r].y = fmaf(p, vv.y, acc[r].y);
            acc[r].z = fmaf(p, vv.z, acc[r].z);
            acc[r].w = fmaf(p, vv.w, acc[r].w);     // vv.w==1 -> denominator
        }
    }

    // block reduction across the 4 waves (each wave had a disjoint key range)
#pragma unroll
    for (int r = 0; r < 4; ++r) sAcc[w * QT_SIZE + r * 64 + lane] = acc[r];
    __syncthreads();

    float4 sum = sAcc[tid];
    float4 p1 = sAcc[QT_SIZE + tid];
    float4 p2 = sAcc[2 * QT_SIZE + tid];
    float4 p3 = sAcc[3 * QT_SIZE + tid];
    sum.x += p1.x + p2.x + p3.x;
    sum.y += p1.y + p2.y + p3.y;
    sum.z += p1.z + p2.z + p3.z;
    sum.w += p1.w + p2.w + p3.w;

    part[((size_t)kb * BHN + bh) * S_LEN + qt * QT_SIZE + tid] = sum;
}

// ---------------- Kernel 2: fused tail ----------------
// partial merge -> o -> theta -> closed-form ring_z -> @wo -> +x -> LN1 ->
// FFN (relu, cos^2) -> +res -> LN2 -> out.
// ring_z closed form: CNOT ring is GF(2)-linear; <Z_0> = prod_{j=1..11} cos(th_j),
// <Z_k> = prod_{j=0..k} cos(th_j) for k>=1.
__global__ __launch_bounds__(128) void tail_kernel(
    const float4* __restrict__ part, const float* __restrict__ x,
    const float* __restrict__ wo, const float* __restrict__ w1, const float* __restrict__ b1,
    const float* __restrict__ w2, const float* __restrict__ b2,
    const float* __restrict__ g1, const float* __restrict__ be1,
    const float* __restrict__ g2, const float* __restrict__ be2,
    float* __restrict__ out)
{
    __shared__ float swo[144], sw1[144], sw2[144];
    __shared__ float sb1[12], sb2[12], sg1[12], sbe1[12], sg2[12], sbe2[12];
    int tid = threadIdx.x;
    for (int i = tid; i < 144; i += 128) { swo[i] = wo[i]; sw1[i] = w1[i]; sw2[i] = w2[i]; }
    if (tid < 12) {
        sb1[tid] = b1[tid]; sb2[tid] = b2[tid];
        sg1[tid] = g1[tid]; sbe1[tid] = be1[tid];
        sg2[tid] = g2[tid]; sbe2[tid] = be2[tid];
    }
    __syncthreads();

    int t = blockIdx.x * 128 + tid;          // token
    int b = t >> 11;
    int s = t & (S_LEN - 1);

    // merge key-split partials, finish softmax division
    float o[12];
#pragma unroll
    for (int h = 0; h < NH; ++h) {
        int bh = b * NH + h;
        float ax = 0, ay = 0, az = 0, aw = 0;
#pragma unroll
        for (int kb = 0; kb < NKB; ++kb) {
            float4 p = part[((size_t)kb * BHN + bh) * S_LEN + s];
            ax += p.x; ay += p.y; az += p.z; aw += p.w;
        }
        float inv = 1.0f / aw;
        o[h * 3 + 0] = ax * inv;
        o[h * 3 + 1] = ay * inv;
        o[h * 3 + 2] = az * inv;
    }

    // theta_k = o_k + o_{k%3}; c_k = cos(theta_k)
    float c[12];
#pragma unroll
    for (int k = 0; k < 12; ++k) c[k] = __cosf(o[k] + o[k % 3]);

    // ring_z closed form
    float z[12];
    {
        float p = c[0];
#pragma unroll
        for (int k = 1; k < 12; ++k) { p *= c[k]; z[k] = p; }
        p = c[1];
#pragma unroll
        for (int k = 2; k < 12; ++k) p *= c[k];
        z[0] = p;
    }

    // attn_out = z @ wo ; residual with x
    const float4* xp = (const float4*)(x + (size_t)t * E_DIM);
    float4 xa = xp[0], xb = xp[1], xc = xp[2];
    float xr[12] = {xa.x, xa.y, xa.z, xa.w, xb.x, xb.y, xb.z, xb.w, xc.x, xc.y, xc.z, xc.w};

    float y[12];
#pragma unroll
    for (int e = 0; e < 12; ++e) {
        float ao = 0;
#pragma unroll
        for (int k = 0; k < 12; ++k) ao = fmaf(z[k], swo[k * 12 + e], ao);
        y[e] = xr[e] + ao;
    }

    // LN1
    float mu = 0;
#pragma unroll
    for (int e = 0; e < 12; ++e) mu += y[e];
    mu *= (1.0f / 12.0f);
    float var = 0;
#pragma unroll
    for (int e = 0; e < 12; ++e) { float d = y[e] - mu; var = fmaf(d, d, var); }
    var *= (1.0f / 12.0f);
    float rs = rsqrtf(var + 1e-5f);
    float x1v[12];
#pragma unroll
    for (int e = 0; e < 12; ++e) x1v[e] = (y[e] - mu) * rs * sg1[e] + sbe1[e];

    // FFN: relu -> cos^2 -> w2
    float zq[12];
#pragma unroll
    for (int f = 0; f < 12; ++f) {
        float hd = sb1[f];
#pragma unroll
        for (int e = 0; e < 12; ++e) hd = fmaf(x1v[e], sw1[e * 12 + f], hd);
        hd = fmaxf(hd, 0.0f);
        float cc = __cosf(hd);
        zq[f] = cc * cc;
    }
    float y2[12];
#pragma unroll
    for (int e = 0; e < 12; ++e) {
        float fo = sb2[e];
#pragma unroll
        for (int f = 0; f < 12; ++f) fo = fmaf(zq[f], sw2[f * 12 + e], fo);
        y2[e] = x1v[e] + fo;
    }

    // LN2 -> out
    float mu2 = 0;
#pragma unroll
    for (int e = 0; e < 12; ++e) mu2 += y2[e];
    mu2 *= (1.0f / 12.0f);
    float var2 = 0;
#pragma unroll
    for (int e = 0; e < 12; ++e) { float d = y2[e] - mu2; var2 = fmaf(d, d, var2); }
    var2 *= (1.0f / 12.0f);
    float rs2 = rsqrtf(var2 + 1e-5f);

    float res[12];
#pragma unroll
    for (int e = 0; e < 12; ++e) res[e] = (y2[e] - mu2) * rs2 * sg2[e] + sbe2[e];

    float4* op = (float4*)(out + (size_t)t * E_DIM);
    op[0] = make_float4(res[0], res[1], res[2], res[3]);
    op[1] = make_float4(res[4], res[5], res[6], res[7]);
    op[2] = make_float4(res[8], res[9], res[10], res[11]);
}

extern "C" void kernel_launch(void* const* d_in, const int* in_sizes, int n_in,
                              void* d_out, int out_size, void* d_ws, size_t ws_size,
                              hipStream_t stream)
{
    const float* x   = (const float*)d_in[0];
    const float* wq  = (const float*)d_in[1];
    const float* wk  = (const float*)d_in[2];
    const float* wv  = (const float*)d_in[3];
    const float* wo  = (const float*)d_in[4];
    const float* w1  = (const float*)d_in[5];
    const float* b1  = (const float*)d_in[6];
    const float* w2  = (const float*)d_in[7];
    const float* b2  = (const float*)d_in[8];
    const float* g1  = (const float*)d_in[9];
    const float* be1 = (const float*)d_in[10];
    const float* g2  = (const float*)d_in[11];
    const float* be2 = (const float*)d_in[12];

    float4* part = (float4*)d_ws;   // NKB*BHN*S_LEN float4

    attn_kernel<<<BHN * NQT * NKB, 256, 0, stream>>>(x, wq, wk, wv, part);
    tail_kernel<<<64, 128, 0, stream>>>(part, x, wo, w1, b1, w2, b2,
                                        g1, be1, g2, be2, (float*)d_out);
}